// Round 7
// baseline (6327.305 us; speedup 1.0000x reference)
//
#include <hip/hip_runtime.h>
#include <stdint.h>

#define TSTEPS 500
#define NB 128
#define NH 256
#define RINGN 8

typedef _Float16 f16;
typedef _Float16 f16x8 __attribute__((ext_vector_type(8)));
typedef float f32x4 __attribute__((ext_vector_type(4)));
typedef unsigned long long u64;
typedef unsigned int u32;

// ---------------- workspace layout ----------------
static constexpr size_t HSLOT = (size_t)NB*NH;                    // 32768 f16 per (layer,t) slot
static constexpr size_t SZ_XCAT  = (size_t)TSTEPS*NB*256*2;       // 32.77 MB
static constexpr size_t SZ_WPACK = (size_t)6*8*128*512*2;         // 6.29 MB
static constexpr size_t SZ_BPACK = (size_t)6*8*128*4;
static constexpr size_t SZ_HNEXT = (size_t)6*RINGN*HSLOT*2;       // 3.15 MB (MALL-coherent ring)
static constexpr size_t SZ_HLOC  = (size_t)6*RINGN*HSLOT*2;       // 3.15 MB (XCD-local L2 ring)
static constexpr size_t SZ_FLAG  = (size_t)6*(TSTEPS+1)*32*4;     // per-wave flags, value = xcc+1
static constexpr size_t SZ_RNN   = (size_t)NB*512*4;
static constexpr size_t OFF_XCAT  = 0;
static constexpr size_t OFF_WPACK = OFF_XCAT + SZ_XCAT;
static constexpr size_t OFF_BPACK = OFF_WPACK + SZ_WPACK;
static constexpr size_t OFF_HNEXT = OFF_BPACK + SZ_BPACK;
static constexpr size_t OFF_HLOC  = OFF_HNEXT + SZ_HNEXT;
static constexpr size_t OFF_FLAGL = OFF_HLOC + SZ_HLOC;
static constexpr size_t OFF_FLAGN = OFF_FLAGL + SZ_FLAG;
static constexpr size_t OFF_RNN   = (OFF_FLAGN + SZ_FLAG + 255) & ~(size_t)255;
static constexpr size_t WS_NEED   = OFF_RNN + SZ_RNN;             // ~46.5 MB (proven budget)

// ---------------- prep: embed + concat + pad, cast f16 ----------------
__global__ void embed_kernel(const int* __restrict__ words,
                             const int* __restrict__ caps,
                             const float* __restrict__ emb,
                             const float* __restrict__ capt,
                             f16* __restrict__ xcat) {
  int t = blockIdx.x >> 7, b = blockIdx.x & 127, k = threadIdx.x;
  int w  = words[b*TSTEPS + t];
  int cp = caps [b*TSTEPS + t];
  float v = 0.f;
  if (k < 200)      v = emb[(size_t)w*200 + k];
  else if (k < 203) v = capt[cp*3 + (k-200)];
  xcat[((size_t)t*NB + b)*256 + k] = (f16)v;
}

// ---------------- prep: pack weights per (layer,wg) (R5/R6-proven) ----------------
__global__ void pack_kernel(const float* __restrict__ Wf0, const float* __restrict__ bf0,
                            const float* __restrict__ Wf1, const float* __restrict__ bf1,
                            const float* __restrict__ Wf2, const float* __restrict__ bf2,
                            const float* __restrict__ Wb0, const float* __restrict__ bb0,
                            const float* __restrict__ Wb1, const float* __restrict__ bb1,
                            const float* __restrict__ Wb2, const float* __restrict__ bb2,
                            f16* __restrict__ wpack, float* __restrict__ bpack) {
  int bid = blockIdx.x;
  int n = bid & 127, wg = (bid >> 7) & 7, layer = bid >> 10;
  const float* W; const float* bb;
  switch (layer) {
    case 0: W = Wf0; bb = bf0; break;
    case 1: W = Wf1; bb = bf1; break;
    case 2: W = Wf2; bb = bf2; break;
    case 3: W = Wb0; bb = bb0; break;
    case 4: W = Wb1; bb = bb1; break;
    default: W = Wb2; bb = bb2; break;
  }
  int level = layer % 3;
  int nt = n >> 4, lcn = n & 15;
  int gate = nt >> 1, np = nt & 1;
  int col = gate*256 + wg*32 + 2*lcn + np;
  if (threadIdx.x == 0)
    bpack[((layer*8 + wg) << 7) + n] = bb[col] + (gate == 2 ? 1.f : 0.f);
  size_t base = ((size_t)(layer*8 + wg)*128 + n)*512;
  for (int k = threadIdx.x; k < 512; k += 256) {
    int row;
    if (level == 0) row = (k < 203) ? k : ((k < 256) ? -1 : k - 53);
    else            row = k;
    float v = (row < 0) ? 0.f : W[(size_t)row*1024 + col];
    int idx = (((k >> 3) ^ (n & 7)) << 3) + (k & 7);
    wpack[base + idx] = (f16)v;
  }
}

// ---------------- prep: flags + hnext ring slot0 = h_0 = 0 ----------------
__global__ void init_kernel(int* __restrict__ flagL, int* __restrict__ flagN,
                            f16* __restrict__ hnext) {
  int i = blockIdx.x*256 + threadIdx.x;
  if (i < 6*(TSTEPS+1)*32) {
    int t = (i >> 5) % (TSTEPS+1);
    flagL[i] = 0;                                  // fast path impossible until first post
    flagN[i] = (t == 0) ? 9 : 0;                   // 9 = ready, never matches xcc+1 in [1,8]
  }
  if (i < 98304) {                                 // hnext slot 0 = zeros per layer
    int l = i >> 14, e = i & 16383;
    ((u32*)(hnext + (size_t)l*RINGN*HSLOT))[e] = 0u;
  }
}

// ---------------- helpers ----------------
__device__ __forceinline__ int poll_agent(const int* q) {     // replicated 8 slots over 64 lanes
  int v;
  for (;;) {
    v = __hip_atomic_load(q, __ATOMIC_RELAXED, __HIP_MEMORY_SCOPE_AGENT);
    if (__all(v != 0)) break;
    __builtin_amdgcn_s_sleep(1);
  }
  return v;
}
__device__ __forceinline__ int ld_flag_l(const int* p) {      // sc0: L1-bypass, shared-L2 read
  int v;
  asm volatile("global_load_dword %0, %1, off sc0\n\ts_waitcnt vmcnt(0)"
               : "=v"(v) : "v"(p) : "memory");
  return v;
}
__device__ __forceinline__ f16x8 ld_a_l(const f16* p) {       // 16B same-XCD L2 load
  f16x8 v;
  asm volatile("global_load_dwordx4 %0, %1, off sc0" : "=v"(v) : "v"(p));
  return v;
}
__device__ __forceinline__ f16x8 ldA_coh(const f16* p) {      // cross-XCD via MALL (R2-proven)
  union { u64 q[2]; f16x8 v; } u;
  u.q[0] = __hip_atomic_load((const u64*)p,     __ATOMIC_RELAXED, __HIP_MEMORY_SCOPE_AGENT);
  u.q[1] = __hip_atomic_load((const u64*)p + 1, __ATOMIC_RELAXED, __HIP_MEMORY_SCOPE_AGENT);
  return u.v;
}
__device__ __forceinline__ void st_flag_plain(int* p, int v) {
  asm volatile("global_store_dword %0, %1, off" :: "v"(p), "v"(v) : "memory");
}
__device__ __forceinline__ void vm_drain() {
  asm volatile("s_waitcnt vmcnt(0)" ::: "memory");
  __builtin_amdgcn_sched_barrier(0);
}
__device__ __forceinline__ void vm_wait8() {                  // oldest-8 (hloc) complete
  asm volatile("s_waitcnt vmcnt(8)" ::: "memory");
  __builtin_amdgcn_sched_barrier(0);
}
__device__ __forceinline__ u32 packh2(float a, float b) {
  union { f16 h[2]; u32 u; } x;
  x.h[0] = (f16)a; x.h[1] = (f16)b;
  return x.u;
}
__device__ __forceinline__ float sigf(float x) {
  return __builtin_amdgcn_rcpf(1.f + __expf(-x));
}
__device__ __forceinline__ float tanhf_(float x) {
  float e = __expf(-2.f*fabsf(x));
  float r = (1.f - e) * __builtin_amdgcn_rcpf(1.f + e);
  return x < 0.f ? -r : r;
}

// grid = 64 (blockIdx = wg*8 + layer; layer>=6 exits), block = 256 (4 waves), dynLDS = 128KB.
// Wave wv owns rows [wv*32,+32) x ALL 128 gate-cols; 4 wv-cohorts = independent pipelines.
// KEY STRUCTURE (R7): the input-half GEMM for step t+1 runs at the TAIL of step t (after the
// flag post), so the h-recurrence critical chain is only: detect -> aH -> recGEMM -> cell ->
// store -> flag. aI/aH register arrays have disjoint liveness (VGPR-bounded, unlike R3).
__global__ __launch_bounds__(256, 1)
void lstm_pipeline(const f16* __restrict__ xcat, const f16* __restrict__ wpack,
                   const float* __restrict__ bpack, f16* hnext, f16* hloc,
                   int* flagL, int* flagN, float* __restrict__ rnn_out) {
  const int layer = blockIdx.x & 7, wg = blockIdx.x >> 3;
  if (layer >= 6) return;
  extern __shared__ char smem[];
  const int stack = layer/3, level = layer - stack*3;

  { // weights -> LDS (swizzled image, linear copy)
    const uint4* src = (const uint4*)(wpack + (size_t)(layer*8 + wg)*128*512);
    uint4* dst = (uint4*)smem;
    for (int i = threadIdx.x; i < 8192; i += 256) dst[i] = src[i];
  }
  const int lane = threadIdx.x & 63, wv = threadIdx.x >> 6;
  const int lc = lane & 15, akg = lane >> 4, bx = lc & 7;
  const int lw = (lane & 7)*4 + wv;                 // replicated flag-slot index (8 WGs x wv)
  const int xcp1 = ((int)__builtin_amdgcn_s_getreg((31 << 11) | 20) & 7) + 1;  // HW_REG_XCC_ID

  float bI[2], bJ[2], bF[2], bO[2];
  {
    const float* bb = bpack + ((size_t)(layer*8 + wg) << 7);
    #pragma unroll
    for (int np = 0; np < 2; ++np) {
      bI[np] = bb[(0*2 + np)*16 + lc];
      bJ[np] = bb[(1*2 + np)*16 + lc];
      bF[np] = bb[(2*2 + np)*16 + lc];
      bO[np] = bb[(3*2 + np)*16 + lc];
    }
  }
  __syncthreads();

  int*       flL  = flagL + (size_t)layer*(TSTEPS+1)*32;
  int*       flN  = flagN + (size_t)layer*(TSTEPS+1)*32;
  const int* flNp = flagN + (size_t)(layer-1)*(TSTEPS+1)*32;
  const int* flNn = flagN + (size_t)(layer+1)*(TSTEPS+1)*32;

  const size_t aoffL = ((size_t)(wv*32 + lc))*256 + (size_t)akg*8;

  float c_st[2][2][4], hmx[2][2][4];
  #pragma unroll
  for (int mt = 0; mt < 2; ++mt)
    #pragma unroll
    for (int np = 0; np < 2; ++np)
      #pragma unroll
      for (int r = 0; r < 4; ++r) { c_st[mt][np][r] = 0.f; hmx[mt][np][r] = -2.f; }

  f32x4 acc[2][8];
  #pragma unroll
  for (int mt = 0; mt < 2; ++mt)
    #pragma unroll
    for (int nt = 0; nt < 8; ++nt) acc[mt][nt] = (f32x4){0.f,0.f,0.f,0.f};

  int prev_ok = 0;
  bool prev_l2 = false;

  // ===== input-half GEMM for a given step: loads aI then accumulates into acc =====
#define IN_GEMM(T)                                                                          \
  do {                                                                                      \
    f16x8 aI0[8], aI1[8];                                                                   \
    if (level == 0) {                                                                       \
      const f16* A_ = xcat + (size_t)(stack ? (TSTEPS - (T)) : ((T)-1))*NB*256 + aoffL;     \
      _Pragma("unroll")                                                                     \
      for (int k8 = 0; k8 < 8; ++k8) {                                                      \
        aI0[k8] = *(const f16x8*)(A_ + k8*32);                                              \
        aI1[k8] = *(const f16x8*)(A_ + 16*256 + k8*32);                                     \
      }                                                                                     \
    } else {                                                                                \
      const size_t off_ = ((size_t)(layer-1)*RINGN + (size_t)((T) & (RINGN-1)))*HSLOT + aoffL; \
      if (prev_l2) {                                                                       \
        const f16* A_ = hloc + off_;                                                        \
        _Pragma("unroll")                                                                   \
        for (int k8 = 0; k8 < 8; ++k8) {                                                    \
          aI0[k8] = ld_a_l(A_ + k8*32);                                                     \
          aI1[k8] = ld_a_l(A_ + 16*256 + k8*32);                                            \
        }                                                                                   \
      } else {                                                                              \
        const f16* A_ = hnext + off_;                                                       \
        _Pragma("unroll")                                                                   \
        for (int k8 = 0; k8 < 8; ++k8) {                                                    \
          aI0[k8] = ldA_coh(A_ + k8*32);                                                    \
          aI1[k8] = ldA_coh(A_ + 16*256 + k8*32);                                           \
        }                                                                                   \
      }                                                                                     \
    }                                                                                       \
    /* backpressure poll overlaps aI flight (p=2, L=5, R=8: R>=p+L-1 ok) */                 \
    if (level < 2 && (T) >= 8 && ((T) & 1) == 0)                                            \
      poll_agent(flNn + (size_t)((T)-6)*32 + lw);                                           \
    vm_drain();                                                                             \
    _Pragma("unroll")                                                                       \
    for (int k8 = 0; k8 < 8; ++k8) {                                                        \
      const int swz0 = ((k8*4 + akg) ^ bx) << 4;                                            \
      _Pragma("unroll")                                                                     \
      for (int nt = 0; nt < 8; ++nt) {                                                      \
        f16x8 vb0 = *(const f16x8*)(smem + (nt*16 + lc)*1024 + swz0);                       \
        acc[0][nt] = __builtin_amdgcn_mfma_f32_16x16x32_f16(aI0[k8], vb0, acc[0][nt],0,0,0); \
        acc[1][nt] = __builtin_amdgcn_mfma_f32_16x16x32_f16(aI1[k8], vb0, acc[1][nt],0,0,0); \
      }                                                                                     \
    }                                                                                       \
  } while (0)

  // ---- preload: inGEMM(1) before entering the recurrence loop ----
  if (level) {
    int tt = (3 > TSTEPS) ? TSTEPS : 3;
    int v = poll_agent(flNp + (size_t)tt*32 + lw);
    prev_l2 = __all(v == xcp1);
    prev_ok = tt;
  }
  IN_GEMM(1);

  for (int t = 1; t <= TSTEPS; ++t) {
    // A. own-poll(t-1): sc0/L2 fast path, MALL fallback each spin (liveness-safe)
    bool fast;
    {
      const int* qL = flL + (size_t)(t-1)*32 + lw;
      const int* qN = flN + (size_t)(t-1)*32 + lw;
      for (;;) {
        int vL = ld_flag_l(qL);                     // includes vmcnt(0)
        if (__all(vL == xcp1)) { fast = true; break; }
        int vN = __hip_atomic_load(qN, __ATOMIC_RELAXED, __HIP_MEMORY_SCOPE_AGENT);
        if (__all(vN != 0)) { fast = false; break; }
        __builtin_amdgcn_s_sleep(1);
      }
    }
    __builtin_amdgcn_sched_barrier(0);

    // B. issue aH (own h_{t-1}), then rec-half GEMM (the critical chain)
    {
      f16x8 aH0[8], aH1[8];
      const size_t off = ((size_t)layer*RINGN + (size_t)((t-1) & (RINGN-1)))*HSLOT + aoffL;
      if (fast) {
        const f16* A = hloc + off;
        #pragma unroll
        for (int k8 = 0; k8 < 8; ++k8) {
          aH0[k8] = ld_a_l(A + k8*32);
          aH1[k8] = ld_a_l(A + 16*256 + k8*32);
        }
      } else {
        const f16* A = hnext + off;
        #pragma unroll
        for (int k8 = 0; k8 < 8; ++k8) {
          aH0[k8] = ldA_coh(A + k8*32);
          aH1[k8] = ldA_coh(A + 16*256 + k8*32);
        }
      }
      vm_drain();                                   // aH valid (rule #18)
      #pragma unroll
      for (int k8 = 0; k8 < 8; ++k8) {              // recurrent half (kword 32..63)
        const int swz1 = ((32 + k8*4 + akg) ^ bx) << 4;
        #pragma unroll
        for (int nt = 0; nt < 8; ++nt) {
          f16x8 vb1 = *(const f16x8*)(smem + (nt*16 + lc)*1024 + swz1);
          acc[0][nt] = __builtin_amdgcn_mfma_f32_16x16x32_f16(aH0[k8], vb1, acc[0][nt],0,0,0);
          acc[1][nt] = __builtin_amdgcn_mfma_f32_16x16x32_f16(aH1[k8], vb1, acc[1][nt],0,0,0);
        }
      }
    }

    // C. cell update (lane-local) into packed registers
    u32 pk[2][4];
    #pragma unroll
    for (int mt = 0; mt < 2; ++mt) {
      #pragma unroll
      for (int r = 0; r < 4; ++r) {
        float hv[2];
        #pragma unroll
        for (int np = 0; np < 2; ++np) {
          float zi = acc[mt][0 + np][r] + bI[np];
          float zj = acc[mt][2 + np][r] + bJ[np];
          float zf = acc[mt][4 + np][r] + bF[np];    // +1 already folded
          float zo = acc[mt][6 + np][r] + bO[np];
          float cs = sigf(zf)*c_st[mt][np][r] + sigf(zi)*tanhf_(zj);
          c_st[mt][np][r] = cs;
          float h = sigf(zo)*tanhf_(cs);
          hv[np] = h;
          if (level == 2) hmx[mt][np][r] = fmaxf(hmx[mt][np][r], h);
        }
        pk[mt][r] = packh2(hv[0], hv[1]);
      }
    }

    // D. stores: 8 hloc (L2) first, 8 hnext (MALL) second; vmcnt(8) waits hloc only
    {
      const size_t obase = ((size_t)layer*RINGN + (size_t)(t & (RINGN-1)))*HSLOT;
      u32* hl32 = (u32*)(hloc  + obase);
      u32* hn32 = (u32*)(hnext + obase);
      #pragma unroll
      for (int mt = 0; mt < 2; ++mt)
        #pragma unroll
        for (int r = 0; r < 4; ++r) {
          int row = wv*32 + mt*16 + akg*4 + r;
          hl32[(size_t)row*128 + wg*16 + lc] = pk[mt][r];
        }
      asm volatile("" ::: "memory");                // keep hloc stores before hnext in queue
      __builtin_amdgcn_sched_barrier(0);
      #pragma unroll
      for (int mt = 0; mt < 2; ++mt)
        #pragma unroll
        for (int r = 0; r < 4; ++r) {
          int row = wv*32 + mt*16 + akg*4 + r;
          __hip_atomic_store(&hn32[(size_t)row*128 + wg*16 + lc], pk[mt][r],
                             __ATOMIC_RELAXED, __HIP_MEMORY_SCOPE_AGENT);
        }
      __builtin_amdgcn_sched_barrier(0);
    }
    vm_wait8();                                     // hloc visible in L2
    if (lane == 0) st_flag_plain(flL + (size_t)t*32 + wg*4 + wv, xcp1);
    vm_drain();                                     // hnext acked at MALL
    if (lane == 0)
      __hip_atomic_store(flN + (size_t)t*32 + wg*4 + wv, xcp1,
                         __ATOMIC_RELAXED, __HIP_MEMORY_SCOPE_AGENT);

    // E. TAIL (off the recurrence chain): prep inGEMM(t+1) into freshly-zeroed acc
    if (t < TSTEPS) {
      #pragma unroll
      for (int mt = 0; mt < 2; ++mt)
        #pragma unroll
        for (int nt = 0; nt < 8; ++nt) acc[mt][nt] = (f32x4){0.f,0.f,0.f,0.f};
      if (level && prev_ok < t + 1) {               // batch prev poll: +3 lookahead, period 3
        int tt = (t + 3 > TSTEPS) ? TSTEPS : t + 3;
        int v = poll_agent(flNp + (size_t)tt*32 + lw);
        prev_l2 = __all(v == xcp1);
        prev_ok = tt;
      }
      IN_GEMM(t + 1);
    }
  }
#undef IN_GEMM

  if (level == 2) {
    #pragma unroll
    for (int mt = 0; mt < 2; ++mt)
      #pragma unroll
      for (int r = 0; r < 4; ++r)
        #pragma unroll
        for (int np = 0; np < 2; ++np)
          rnn_out[(size_t)(wv*32 + mt*16 + akg*4 + r)*512 + stack*256 + wg*32 + 2*lc + np]
              = hmx[mt][np][r];
  }
}

// ---------------- epilogue: elu(rnn@W1+b1)@W2+b2 -> sigmoid ----------------
__global__ __launch_bounds__(256)
void dense_kernel(const float* __restrict__ rnn, const float* __restrict__ W1,
                  const float* __restrict__ b1, const float* __restrict__ W2,
                  const float* __restrict__ b2, float* __restrict__ out) {
  __shared__ float h1[16][64];
  int r0 = blockIdx.x*16;
  int c = threadIdx.x & 63, rr = threadIdx.x >> 6;
  #pragma unroll
  for (int m = 0; m < 4; ++m) {
    int rl = rr*4 + m;
    const float* rp = rnn + (size_t)(r0 + rl)*512;
    float s = b1[c];
    for (int k = 0; k < 512; ++k) s = fmaf(rp[k], W1[(size_t)k*64 + c], s);
    h1[rl][c] = (s > 0.f) ? s : (__expf(s) - 1.f);
  }
  __syncthreads();
  if (threadIdx.x < 96) {
    int rl = threadIdx.x/6, cc = threadIdx.x - rl*6;
    float s = b2[cc];
    #pragma unroll
    for (int k = 0; k < 64; ++k) s = fmaf(h1[rl][k], W2[k*6 + cc], s);
    out[(size_t)(r0 + rl)*6 + cc] = 1.f/(1.f + __expf(-s));
  }
}

// ---------------- launch ----------------
extern "C" void kernel_launch(void* const* d_in, const int* in_sizes, int n_in,
                              void* d_out, int out_size, void* d_ws, size_t ws_size,
                              hipStream_t stream) {
  if (ws_size < WS_NEED) return;  // clean failure instead of corruption
  const int*   words = (const int*)d_in[0];
  const int*   caps  = (const int*)d_in[1];
  const float* emb   = (const float*)d_in[2];
  const float* capt  = (const float*)d_in[3];
  char* ws = (char*)d_ws;
  f16*   xcat  = (f16*)  (ws + OFF_XCAT);
  f16*   wpack = (f16*)  (ws + OFF_WPACK);
  float* bpack = (float*)(ws + OFF_BPACK);
  f16*   hnext = (f16*)  (ws + OFF_HNEXT);
  f16*   hloc  = (f16*)  (ws + OFF_HLOC);
  int*   flagL = (int*)  (ws + OFF_FLAGL);
  int*   flagN = (int*)  (ws + OFF_FLAGN);
  float* rnn   = (float*)(ws + OFF_RNN);

  embed_kernel<<<TSTEPS*NB, 256, 0, stream>>>(words, caps, emb, capt, xcat);
  pack_kernel<<<6*8*128, 256, 0, stream>>>(
      (const float*)d_in[4],  (const float*)d_in[5],  (const float*)d_in[6],  (const float*)d_in[7],
      (const float*)d_in[8],  (const float*)d_in[9],  (const float*)d_in[10], (const float*)d_in[11],
      (const float*)d_in[12], (const float*)d_in[13], (const float*)d_in[14], (const float*)d_in[15],
      wpack, bpack);
  init_kernel<<<768, 256, 0, stream>>>(flagL, flagN, hnext);
  lstm_pipeline<<<64, 256, 131072, stream>>>(xcat, wpack, bpack, hnext, hloc,
                                             flagL, flagN, rnn);
  dense_kernel<<<8, 256, 0, stream>>>(rnn, (const float*)d_in[16], (const float*)d_in[17],
                                      (const float*)d_in[18], (const float*)d_in[19], (float*)d_out);
}

// Round 8
// 4998.848 us; speedup vs baseline: 1.2658x; 1.2658x over previous
//
#include <hip/hip_runtime.h>
#include <stdint.h>

#define TSTEPS 500
#define NB 128
#define NH 256
#define RINGN 8
#define NWG 16   // workgroups per layer (each: 16 units x 4 gates = 64 gate-cols)

typedef _Float16 f16;
typedef _Float16 f16x8 __attribute__((ext_vector_type(8)));
typedef float f32x4 __attribute__((ext_vector_type(4)));
typedef unsigned long long u64;
typedef unsigned int u32;

// ---------------- workspace layout ----------------
static constexpr size_t HSLOT = (size_t)NB*NH;                      // 32768 f16 per (layer,t)
static constexpr size_t SZ_XCAT  = (size_t)TSTEPS*NB*256*2;         // 32.77 MB
static constexpr size_t SZ_WLDS  = (size_t)6*NWG*64*256*2;          // 3.15 MB input-half LDS image
static constexpr size_t SZ_WREG  = (size_t)6*NWG*4*8*64*8*2;        // 3.15 MB rec-half reg image
static constexpr size_t SZ_BIAS  = (size_t)6*NWG*64*4;
static constexpr size_t SZ_HNEXT = (size_t)6*RINGN*HSLOT*2;         // MALL-coherent ring
static constexpr size_t SZ_HLOC  = (size_t)6*RINGN*HSLOT*2;         // XCD-local L2 ring
static constexpr size_t SZ_FLAG  = (size_t)6*(TSTEPS+1)*64*4;       // per-wave flags (16wg x 4wv)
static constexpr size_t SZ_RNN   = (size_t)NB*512*4;
static constexpr size_t OFF_XCAT  = 0;
static constexpr size_t OFF_WLDS  = OFF_XCAT + SZ_XCAT;
static constexpr size_t OFF_WREG  = OFF_WLDS + SZ_WLDS;
static constexpr size_t OFF_BIAS  = OFF_WREG + SZ_WREG;
static constexpr size_t OFF_HNEXT = OFF_BIAS + SZ_BIAS;
static constexpr size_t OFF_HLOC  = OFF_HNEXT + SZ_HNEXT;
static constexpr size_t OFF_FLAGL = OFF_HLOC + SZ_HLOC;
static constexpr size_t OFF_FLAGN = OFF_FLAGL + SZ_FLAG;
static constexpr size_t OFF_RNN   = (OFF_FLAGN + SZ_FLAG + 255) & ~(size_t)255;
static constexpr size_t WS_NEED   = OFF_RNN + SZ_RNN;               // ~47.4 MB

// ---------------- prep: embed + concat + pad, cast f16 ----------------
__global__ void embed_kernel(const int* __restrict__ words,
                             const int* __restrict__ caps,
                             const float* __restrict__ emb,
                             const float* __restrict__ capt,
                             f16* __restrict__ xcat) {
  int t = blockIdx.x >> 7, b = blockIdx.x & 127, k = threadIdx.x;
  int w  = words[b*TSTEPS + t];
  int cp = caps [b*TSTEPS + t];
  float v = 0.f;
  if (k < 200)      v = emb[(size_t)w*200 + k];
  else if (k < 203) v = capt[cp*3 + (k-200)];
  xcat[((size_t)t*NB + b)*256 + k] = (f16)v;
}

// ---------------- prep: pack weights ----------------
// part1 (bid<6144): input-half LDS image per (layer,wg,n): n = g*16+u -> col g*256+wg*16+u,
//   k 0..255 (level0: rows 0..202 + pad), 16B-block XOR swizzle within each 512B column.
// part2 (bid>=6144): rec-half register image [layer][wg][g][ks][lane][8]:
//   lane -> B frag (col = g*256+wg*16+(lane&15), k = ks*32+(lane>>4)*8+j), rec row base 203/256.
__global__ void pack_kernel(const float* __restrict__ Wf0, const float* __restrict__ bf0,
                            const float* __restrict__ Wf1, const float* __restrict__ bf1,
                            const float* __restrict__ Wf2, const float* __restrict__ bf2,
                            const float* __restrict__ Wb0, const float* __restrict__ bb0,
                            const float* __restrict__ Wb1, const float* __restrict__ bb1,
                            const float* __restrict__ Wb2, const float* __restrict__ bb2,
                            f16* __restrict__ wlds, f16* __restrict__ wreg,
                            float* __restrict__ bias) {
  int bid = blockIdx.x;
  int layer, wg;
  const float* W; const float* bb;
  int part1 = (bid < 6144);
  if (part1) layer = bid >> 10;
  else       layer = (bid - 6144) >> 6;
  switch (layer) {
    case 0: W = Wf0; bb = bf0; break;
    case 1: W = Wf1; bb = bf1; break;
    case 2: W = Wf2; bb = bf2; break;
    case 3: W = Wb0; bb = bb0; break;
    case 4: W = Wb1; bb = bb1; break;
    default: W = Wb2; bb = bb2; break;
  }
  int level = layer % 3;
  if (part1) {
    wg = (bid >> 6) & 15;
    int n = bid & 63;
    int g = n >> 4, u = n & 15;
    int col = g*256 + wg*16 + u;
    if (threadIdx.x == 0)
      bias[(size_t)(layer*NWG + wg)*64 + n] = bb[col] + (g == 2 ? 1.f : 0.f);
    int k = threadIdx.x;                                    // 0..255
    int row = (level == 0) ? ((k < 203) ? k : -1) : k;
    float v = (row < 0) ? 0.f : W[(size_t)row*1024 + col];
    int idx = (((k >> 3) ^ (n & 7)) << 3) | (k & 7);
    wlds[((size_t)(layer*NWG + wg)*64 + n)*256 + idx] = (f16)v;
  } else {
    int rem = (bid - 6144) & 63;
    wg = rem >> 2;
    int g = rem & 3;
    int lane = threadIdx.x & 63;
    int col = g*256 + wg*16 + (lane & 15);
    int rbase = (level == 0) ? 203 : 256;
    for (int ks = threadIdx.x >> 6; ks < 8; ks += 4) {
      size_t base = ((size_t)((layer*NWG + wg)*4 + g)*8 + ks)*64*8 + (size_t)lane*8;
      #pragma unroll
      for (int j = 0; j < 8; ++j) {
        int k = ks*32 + (lane >> 4)*8 + j;
        wreg[base + j] = (f16)W[(size_t)(rbase + k)*1024 + col];
      }
    }
  }
}

// ---------------- prep: flags + hnext ring slot0 = h_0 = 0 ----------------
__global__ void init_kernel(int* __restrict__ flagL, int* __restrict__ flagN,
                            f16* __restrict__ hnext) {
  int i = blockIdx.x*256 + threadIdx.x;
  if (i < 6*(TSTEPS+1)*64) {
    int t = (i >> 6) % (TSTEPS+1);
    flagL[i] = 0;
    flagN[i] = (t == 0) ? 9 : 0;                  // 9 never matches xcc+1 in [1,8]
  }
  if (i < 98304) {                                // hnext slot 0 = zeros per layer
    int l = i >> 14, e = i & 16383;
    ((u32*)(hnext + (size_t)l*RINGN*HSLOT))[e] = 0u;
  }
}

// ---------------- helpers ----------------
__device__ __forceinline__ int poll_agent(const int* q) {
  int v;
  for (;;) {
    v = __hip_atomic_load(q, __ATOMIC_RELAXED, __HIP_MEMORY_SCOPE_AGENT);
    if (__all(v != 0)) break;
    __builtin_amdgcn_s_sleep(1);
  }
  return v;
}
__device__ __forceinline__ int ld_flag_l(const int* p) {       // sc0: L1-bypass L2 read
  int v;
  asm volatile("global_load_dword %0, %1, off sc0\n\ts_waitcnt vmcnt(0)"
               : "=v"(v) : "v"(p) : "memory");
  return v;
}
__device__ __forceinline__ f16x8 ld_a_l(const f16* p) {        // 16B same-XCD L2 load
  f16x8 v;
  asm volatile("global_load_dwordx4 %0, %1, off sc0" : "=v"(v) : "v"(p));
  return v;
}
__device__ __forceinline__ f16x8 ld_a_p(const f16* p) {        // 16B plain cached load (asm: we count it)
  f16x8 v;
  asm volatile("global_load_dwordx4 %0, %1, off" : "=v"(v) : "v"(p));
  return v;
}
__device__ __forceinline__ f16x8 ldA_coh(const f16* p) {       // cross-XCD via MALL (proven)
  union { u64 q[2]; f16x8 v; } u;
  u.q[0] = __hip_atomic_load((const u64*)p,     __ATOMIC_RELAXED, __HIP_MEMORY_SCOPE_AGENT);
  u.q[1] = __hip_atomic_load((const u64*)p + 1, __ATOMIC_RELAXED, __HIP_MEMORY_SCOPE_AGENT);
  return u.v;
}
__device__ __forceinline__ void st_h_l(f16* p, short s) {      // plain store -> own-XCD L2
  asm volatile("global_store_short %0, %1, off" :: "v"(p), "v"((int)s) : "memory");
}
__device__ __forceinline__ void st_flag_plain(int* p, int v) {
  asm volatile("global_store_dword %0, %1, off" :: "v"(p), "v"(v) : "memory");
}
__device__ __forceinline__ void vm_drain() {
  asm volatile("s_waitcnt vmcnt(0)" ::: "memory");
  __builtin_amdgcn_sched_barrier(0);
}
__device__ __forceinline__ float sigf(float x) {
  return __builtin_amdgcn_rcpf(1.f + __expf(-x));
}
__device__ __forceinline__ float tanhf_(float x) {
  float e = __expf(-2.f*fabsf(x));
  float r = (1.f - e) * __builtin_amdgcn_rcpf(1.f + e);
  return x < 0.f ? -r : r;
}

// grid = 128 (layer = bid&7 -> one layer per XCD; wg = bid>>3 in 0..15), block = 256 (4 waves),
// dynLDS = 32KB (input-half weights). Rec-half B lives in 128 VGPRs/lane for all 500 steps ->
// recGEMM has ZERO LDS reads. Wave wv owns rows [wv*32,+32); lane owns unit wg*16+(lane&15),
// one gate per acc tile -> lane-local cell. Sync = R6-proven dual flag (flagL sc0 / flagN MALL).
__global__ __launch_bounds__(256, 1)
void lstm_pipeline(const f16* __restrict__ xcat, const f16* __restrict__ wlds,
                   const f16* __restrict__ wreg, const float* __restrict__ bias,
                   f16* hnext, f16* hloc, int* flagL, int* flagN,
                   float* __restrict__ rnn_out) {
  const int layer = blockIdx.x & 7, wg = blockIdx.x >> 3;
  if (layer >= 6) return;
  extern __shared__ char smem[];
  const int stack = layer/3, level = layer - stack*3;

  { // input-half weights -> LDS (swizzled image, linear copy)
    const uint4* src = (const uint4*)(wlds + (size_t)(layer*NWG + wg)*64*256);
    uint4* dst = (uint4*)smem;
    for (int i = threadIdx.x; i < 2048; i += 256) dst[i] = src[i];
  }
  const int lane = threadIdx.x & 63, wv = threadIdx.x >> 6;
  const int lc = lane & 15, akg = lane >> 4;
  const int slot16 = lc*4 + wv;                    // poll slot (producer wg' = lc, wave wv)
  const int xcp1 = ((int)__builtin_amdgcn_s_getreg((31 << 11) | 20) & 7) + 1;  // XCC_ID+1

  // rec-half B into registers (128 VGPR/lane, resident for the whole run)
  f16x8 Brec[4][8];
  {
    const f16* wr = wreg + (size_t)(layer*NWG + wg)*4*8*64*8;
    #pragma unroll
    for (int g = 0; g < 4; ++g)
      #pragma unroll
      for (int ks = 0; ks < 8; ++ks)
        Brec[g][ks] = *(const f16x8*)(wr + ((size_t)(g*8 + ks)*64 + lane)*8);
  }
  float bI, bJ, bF, bO;
  {
    const float* bb = bias + (size_t)(layer*NWG + wg)*64;
    bI = bb[0*16 + lc]; bJ = bb[1*16 + lc]; bF = bb[2*16 + lc]; bO = bb[3*16 + lc];
  }
  __syncthreads();

  int*       flL  = flagL + (size_t)layer*(TSTEPS+1)*64;
  int*       flN  = flagN + (size_t)layer*(TSTEPS+1)*64;
  const int* flNp = flagN + (size_t)(layer-1)*(TSTEPS+1)*64;
  const int* flNn = flagN + (size_t)(layer+1)*(TSTEPS+1)*64;

  const size_t aoff = (size_t)(wv*32 + lc)*256 + (size_t)akg*8;  // A frag base (row, k)

  float c_st[2][4], hmx[2][4];
  #pragma unroll
  for (int mt = 0; mt < 2; ++mt)
    #pragma unroll
    for (int r = 0; r < 4; ++r) { c_st[mt][r] = 0.f; hmx[mt][r] = -2.f; }

  f16x8 aI[2][8];                                  // input A for the CURRENT step
  int prev_ok = 0;
  bool prev_l2 = false;

#define LOAD_AI(T)                                                                    \
  do {                                                                                \
    if (level == 0) {                                                                 \
      const f16* A_ = xcat + (size_t)(stack ? (TSTEPS - (T)) : ((T)-1))*NB*256;       \
      _Pragma("unroll")                                                               \
      for (int mt = 0; mt < 2; ++mt)                                                  \
        _Pragma("unroll")                                                             \
        for (int ks = 0; ks < 8; ++ks)                                                \
          aI[mt][ks] = ld_a_p(A_ + aoff + mt*4096 + ks*32);                           \
    } else if (prev_l2) {                                                             \
      const f16* A_ = hloc + ((size_t)(layer-1)*RINGN + (size_t)((T) & 7))*HSLOT;     \
      _Pragma("unroll")                                                               \
      for (int mt = 0; mt < 2; ++mt)                                                  \
        _Pragma("unroll")                                                             \
        for (int ks = 0; ks < 8; ++ks)                                                \
          aI[mt][ks] = ld_a_l(A_ + aoff + mt*4096 + ks*32);                           \
    } else {                                                                          \
      const f16* A_ = hnext + ((size_t)(layer-1)*RINGN + (size_t)((T) & 7))*HSLOT;    \
      _Pragma("unroll")                                                               \
      for (int mt = 0; mt < 2; ++mt)                                                  \
        _Pragma("unroll")                                                             \
        for (int ks = 0; ks < 8; ++ks)                                                \
          aI[mt][ks] = ldA_coh(A_ + aoff + mt*4096 + ks*32);                          \
    }                                                                                 \
  } while (0)

  // ---- prologue: prev lookahead + aI(1) ----
  if (level) {
    int la = 3 > TSTEPS ? TSTEPS : 3;
    int v = poll_agent(flNp + (size_t)la*64 + slot16);
    prev_l2 = __all(v == xcp1);
    prev_ok = la;
  }
  LOAD_AI(1);
  __builtin_amdgcn_sched_barrier(0);

  for (int t = 1; t <= TSTEPS; ++t) {
    // A. own-poll(t-1): sc0 fast path + MALL fallback each spin (R6-proven; vmcnt(0)
    //    inside also drains the aI(t) prefetch and last step's hnext/flag acks)
    bool fast;
    {
      const int* qL = flL + (size_t)(t-1)*64 + slot16;
      const int* qN = flN + (size_t)(t-1)*64 + slot16;
      for (;;) {
        int vL = ld_flag_l(qL);
        if (__all(vL == xcp1)) { fast = true; break; }
        int vN = __hip_atomic_load(qN, __ATOMIC_RELAXED, __HIP_MEMORY_SCOPE_AGENT);
        if (__all(vN != 0)) { fast = false; break; }
        __builtin_amdgcn_s_sleep(1);
      }
    }
    __builtin_amdgcn_sched_barrier(0);
    #pragma unroll
    for (int mt = 0; mt < 2; ++mt)                 // pin aI: compiler-managed loads get their
      #pragma unroll
      for (int ks = 0; ks < 8; ++ks)               // waitcnt HERE, not inside the GEMM
        asm volatile("" :: "v"(aI[mt][ks]));
    __builtin_amdgcn_sched_barrier(0);

    // B. issue 16 aH loads (own h_{t-1}): FIRST into the vm queue
    f16x8 aH[2][8];
    {
      const size_t hb = ((size_t)layer*RINGN + (size_t)((t-1) & 7))*HSLOT;
      if (fast) {
        const f16* A = hloc + hb;
        #pragma unroll
        for (int mt = 0; mt < 2; ++mt)
          #pragma unroll
          for (int ks = 0; ks < 8; ++ks)
            aH[mt][ks] = ld_a_l(A + aoff + mt*4096 + ks*32);
      } else {
        const f16* A = hnext + hb;
        #pragma unroll
        for (int mt = 0; mt < 2; ++mt)
          #pragma unroll
          for (int ks = 0; ks < 8; ++ks)
            aH[mt][ks] = ldA_coh(A + aoff + mt*4096 + ks*32);
      }
    }
    __builtin_amdgcn_sched_barrier(0);

    // C. occasional cross-layer polls (MALL; amortized, overlap aH flight)
    if (level < 2 && t >= 8 && (t & 1) == 0)
      poll_agent(flNn + (size_t)(t-6)*64 + slot16);        // ring-8 backpressure
    int tt = (t + 1 <= TSTEPS) ? t + 1 : TSTEPS;
    if (level && prev_ok < tt) {
      int la = (tt + 2 <= TSTEPS) ? tt + 2 : TSTEPS;
      int v = poll_agent(flNp + (size_t)la*64 + slot16);
      prev_l2 = __all(v == xcp1);
      prev_ok = la;
    }
    __builtin_amdgcn_sched_barrier(0);
    const int nai = (level == 0 || prev_l2) ? 16 : 32;     // #VMEM ops LOAD_AI will issue

    // D. input-half GEMM (aI regs + LDS B): runs while aH flies
    f32x4 acc[2][4];
    #pragma unroll
    for (int mt = 0; mt < 2; ++mt)
      #pragma unroll
      for (int g = 0; g < 4; ++g) acc[mt][g] = (f32x4){0.f,0.f,0.f,0.f};
    #pragma unroll
    for (int ks = 0; ks < 8; ++ks) {
      const int swz = (((ks*4 + akg) ^ (lc & 7)) << 4);
      f16x8 vb0 = *(const f16x8*)(smem + (0*16 + lc)*512 + swz);
      f16x8 vb1 = *(const f16x8*)(smem + (1*16 + lc)*512 + swz);
      f16x8 vb2 = *(const f16x8*)(smem + (2*16 + lc)*512 + swz);
      f16x8 vb3 = *(const f16x8*)(smem + (3*16 + lc)*512 + swz);
      #pragma unroll
      for (int mt = 0; mt < 2; ++mt) {
        acc[mt][0] = __builtin_amdgcn_mfma_f32_16x16x32_f16(aI[mt][ks], vb0, acc[mt][0],0,0,0);
        acc[mt][1] = __builtin_amdgcn_mfma_f32_16x16x32_f16(aI[mt][ks], vb1, acc[mt][1],0,0,0);
        acc[mt][2] = __builtin_amdgcn_mfma_f32_16x16x32_f16(aI[mt][ks], vb2, acc[mt][2],0,0,0);
        acc[mt][3] = __builtin_amdgcn_mfma_f32_16x16x32_f16(aI[mt][ks], vb3, acc[mt][3],0,0,0);
      }
    }
    __builtin_amdgcn_sched_barrier(0);

    // E. issue aI(t+1): SECOND into the queue (flies until next step's poll)
    LOAD_AI(tt);
    __builtin_amdgcn_sched_barrier(0);

    // F. wait aH only (oldest in queue; newest nai = aI(t+1) stay in flight), rec-half GEMM
    if (nai == 16) { asm volatile("s_waitcnt vmcnt(16)" ::: "memory"); }
    else           { asm volatile("s_waitcnt vmcnt(32)" ::: "memory"); }
    __builtin_amdgcn_sched_barrier(0);
    #pragma unroll
    for (int ks = 0; ks < 8; ++ks)
      #pragma unroll
      for (int mt = 0; mt < 2; ++mt) {
        acc[mt][0] = __builtin_amdgcn_mfma_f32_16x16x32_f16(aH[mt][ks], Brec[0][ks], acc[mt][0],0,0,0);
        acc[mt][1] = __builtin_amdgcn_mfma_f32_16x16x32_f16(aH[mt][ks], Brec[1][ks], acc[mt][1],0,0,0);
        acc[mt][2] = __builtin_amdgcn_mfma_f32_16x16x32_f16(aH[mt][ks], Brec[2][ks], acc[mt][2],0,0,0);
        acc[mt][3] = __builtin_amdgcn_mfma_f32_16x16x32_f16(aH[mt][ks], Brec[3][ks], acc[mt][3],0,0,0);
      }

    // G. cell update (fully lane-local: 4 gates of unit wg*16+lc, 8 rows)
    short hh[2][4];
    #pragma unroll
    for (int mt = 0; mt < 2; ++mt) {
      #pragma unroll
      for (int r = 0; r < 4; ++r) {
        float zi = acc[mt][0][r] + bI;
        float zj = acc[mt][1][r] + bJ;
        float zf = acc[mt][2][r] + bF;               // forget +1 folded
        float zo = acc[mt][3][r] + bO;
        float cs = sigf(zf)*c_st[mt][r] + sigf(zi)*tanhf_(zj);
        c_st[mt][r] = cs;
        float h = sigf(zo)*tanhf_(cs);
        if (level == 2) hmx[mt][r] = fmaxf(hmx[mt][r], h);
        union { f16 h; short s; } cv; cv.h = (f16)h;
        hh[mt][r] = cv.s;
      }
    }

    // H. stores: 8 hnext (MALL) + 8 hloc (L2); ONE drain; then both flags
    {
      const size_t ob = ((size_t)layer*RINGN + (size_t)(t & 7))*HSLOT;
      f16* hn = hnext + ob;
      f16* hl = hloc  + ob;
      #pragma unroll
      for (int mt = 0; mt < 2; ++mt)
        #pragma unroll
        for (int r = 0; r < 4; ++r) {
          int row = wv*32 + mt*16 + akg*4 + r;
          __hip_atomic_store((short*)(hn + (size_t)row*256 + wg*16 + lc), hh[mt][r],
                             __ATOMIC_RELAXED, __HIP_MEMORY_SCOPE_AGENT);
        }
      __builtin_amdgcn_sched_barrier(0);
      #pragma unroll
      for (int mt = 0; mt < 2; ++mt)
        #pragma unroll
        for (int r = 0; r < 4; ++r) {
          int row = wv*32 + mt*16 + akg*4 + r;
          st_h_l(hl + (size_t)row*256 + wg*16 + lc, hh[mt][r]);
        }
    }
    vm_drain();                                      // hnext @MALL + hloc @L2 (+ aI residual)
    if (lane == 0) {
      st_flag_plain(flL + (size_t)t*64 + wg*4 + wv, xcp1);
      __hip_atomic_store(flN + (size_t)t*64 + wg*4 + wv, xcp1,
                         __ATOMIC_RELAXED, __HIP_MEMORY_SCOPE_AGENT);
    }
  }
#undef LOAD_AI

  if (level == 2) {
    #pragma unroll
    for (int mt = 0; mt < 2; ++mt)
      #pragma unroll
      for (int r = 0; r < 4; ++r)
        rnn_out[(size_t)(wv*32 + mt*16 + akg*4 + r)*512 + stack*256 + wg*16 + lc]
            = hmx[mt][r];
  }
}

// ---------------- epilogue: elu(rnn@W1+b1)@W2+b2 -> sigmoid ----------------
__global__ __launch_bounds__(256)
void dense_kernel(const float* __restrict__ rnn, const float* __restrict__ W1,
                  const float* __restrict__ b1, const float* __restrict__ W2,
                  const float* __restrict__ b2, float* __restrict__ out) {
  __shared__ float h1[16][64];
  int r0 = blockIdx.x*16;
  int c = threadIdx.x & 63, rr = threadIdx.x >> 6;
  #pragma unroll
  for (int m = 0; m < 4; ++m) {
    int rl = rr*4 + m;
    const float* rp = rnn + (size_t)(r0 + rl)*512;
    float s = b1[c];
    for (int k = 0; k < 512; ++k) s = fmaf(rp[k], W1[(size_t)k*64 + c], s);
    h1[rl][c] = (s > 0.f) ? s : (__expf(s) - 1.f);
  }
  __syncthreads();
  if (threadIdx.x < 96) {
    int rl = threadIdx.x/6, cc = threadIdx.x - rl*6;
    float s = b2[cc];
    #pragma unroll
    for (int k = 0; k < 64; ++k) s = fmaf(h1[rl][k], W2[k*6 + cc], s);
    out[(size_t)(r0 + rl)*6 + cc] = 1.f/(1.f + __expf(-s));
  }
}

// ---------------- launch ----------------
extern "C" void kernel_launch(void* const* d_in, const int* in_sizes, int n_in,
                              void* d_out, int out_size, void* d_ws, size_t ws_size,
                              hipStream_t stream) {
  if (ws_size < WS_NEED) return;  // clean failure instead of corruption
  const int*   words = (const int*)d_in[0];
  const int*   caps  = (const int*)d_in[1];
  const float* emb   = (const float*)d_in[2];
  const float* capt  = (const float*)d_in[3];
  char* ws = (char*)d_ws;
  f16*   xcat  = (f16*)  (ws + OFF_XCAT);
  f16*   wlds  = (f16*)  (ws + OFF_WLDS);
  f16*   wreg  = (f16*)  (ws + OFF_WREG);
  float* bias  = (float*)(ws + OFF_BIAS);
  f16*   hnext = (f16*)  (ws + OFF_HNEXT);
  f16*   hloc  = (f16*)  (ws + OFF_HLOC);
  int*   flagL = (int*)  (ws + OFF_FLAGL);
  int*   flagN = (int*)  (ws + OFF_FLAGN);
  float* rnn   = (float*)(ws + OFF_RNN);

  embed_kernel<<<TSTEPS*NB, 256, 0, stream>>>(words, caps, emb, capt, xcat);
  pack_kernel<<<6144 + 384, 256, 0, stream>>>(
      (const float*)d_in[4],  (const float*)d_in[5],  (const float*)d_in[6],  (const float*)d_in[7],
      (const float*)d_in[8],  (const float*)d_in[9],  (const float*)d_in[10], (const float*)d_in[11],
      (const float*)d_in[12], (const float*)d_in[13], (const float*)d_in[14], (const float*)d_in[15],
      wlds, wreg, bias);
  init_kernel<<<768, 256, 0, stream>>>(flagL, flagN, hnext);
  lstm_pipeline<<<128, 256, 32768, stream>>>(xcat, wlds, wreg, bias, hnext, hloc,
                                             flagL, flagN, rnn);
  dense_kernel<<<8, 256, 0, stream>>>(rnn, (const float*)d_in[16], (const float*)d_in[17],
                                      (const float*)d_in[18], (const float*)d_in[19], (float*)d_out);
}